// Round 6
// baseline (84.396 us; speedup 1.0000x reference)
//
#include <hip/hip_runtime.h>
#include <hip/hip_bf16.h>

typedef float f4 __attribute__((ext_vector_type(4)));
typedef float f32x4 __attribute__((ext_vector_type(4)));
typedef unsigned short u16x8 __attribute__((ext_vector_type(8)));
typedef short short8 __attribute__((ext_vector_type(8)));
typedef unsigned int uint2v __attribute__((ext_vector_type(2)));

#define QSCALE 0.17677669529663689f  // 32^-0.5

__device__ inline float b2f(unsigned short u){
  union{unsigned int i; float f;} z; z.i = ((unsigned int)u)<<16; return z.f;
}
__device__ inline unsigned short f2b(float f){
  union{float f; unsigned int i;} z; z.f=f;
  unsigned int i = z.i;
  return (unsigned short)((i + 0x7FFFu + ((i>>16)&1u)) >> 16);
}

// stage a [128k][128n] fp32 weight panel -> Ws[n][k] bf16, XOR-swizzled (1024 thr)
__device__ inline void stageW(const float* __restrict__ w, int stride, int n0,
                              short* Ws, int t){
  if (t < 1024){
    int kb = t >> 5, nb = t & 31;
    const float* p = &w[(kb*4)*stride + n0 + nb*4];
    f4 r0 = *(const f4*)p;
    f4 r1 = *(const f4*)(p + stride);
    f4 r2 = *(const f4*)(p + 2*stride);
    f4 r3 = *(const f4*)(p + 3*stride);
#pragma unroll
    for (int j = 0; j < 4; ++j){
      int n = nb*4 + j;
      uint2v val;
      val[0] = (unsigned int)f2b(r0[j]) | ((unsigned int)f2b(r1[j])<<16);
      val[1] = (unsigned int)f2b(r2[j]) | ((unsigned int)f2b(r3[j])<<16);
      int byte = (n<<8) + (kb<<3);
      *(uint2v*)((char*)Ws + (byte ^ ((n&7)<<4))) = val;
    }
  }
}

__device__ inline short8 ldB(const short* Ws, int rn, int koff){
  int byte = (rn<<8) + (koff<<1);
  return *(const short8*)((const char*)Ws + (byte ^ ((rn&7)<<4)));
}

__device__ inline short8 ldA(const float* p){
  f4 lo = *(const f4*)p, hi = *(const f4*)(p+4);
  short8 r;
  r[0]=(short)f2b(lo[0]); r[1]=(short)f2b(lo[1]);
  r[2]=(short)f2b(lo[2]); r[3]=(short)f2b(lo[3]);
  r[4]=(short)f2b(hi[0]); r[5]=(short)f2b(hi[1]);
  r[6]=(short)f2b(hi[2]); r[7]=(short)f2b(hi[3]);
  return r;
}

// ============ fully fused neighborhood attention, 16 waves/block ============
// grid (8,8,4) = (tile_j, tile_i, batch), block 1024 (16 waves), 1 block/CU.
__global__ __launch_bounds__(1024) void k_fused(
    const float* __restrict__ x,     const float* __restrict__ wqkv,
    const float* __restrict__ bqkv,  const float* __restrict__ rpb,
    const float* __restrict__ wproj, const float* __restrict__ bproj,
    float* __restrict__ out)
{
  __shared__ short lds[79752];           // 159,504 B
  short* Qs = lds;                       // [64][136]  q, later ao
  short* Ks = lds + 8704;                // [196][136] k halo
  short* Vs = Ks + 26656;                // [196][136] v halo, later fp32 C
  short* Ws = Vs + 26656;                // [128][128] swizzled weight panel
  float* rs = (float*)(Ws + 16384);      // [676] rpb

  const int t  = threadIdx.x;
  const int b  = blockIdx.z;
  const int th0 = blockIdx.y * 8, tw0 = blockIdx.x * 8;
  const int bi0 = min(max(th0-3,0),50), bj0 = min(max(tw0-3,0),50);
  const int wv = t >> 6, l = t & 63;
  const int lr = l & 15, lk = (l >> 4) << 3;

  // phase 0: stage wq panel + rpb
  stageW(wqkv, 384, 0, Ws, t);
  if (t < 676) rs[t] = rpb[t];
  __syncthreads();                                          // S1

  // ---- Q GEMM: wave = (m-frag wv>>2, n-pair wv&3) ----
  {
    const int mq = wv >> 2, g = wv & 3;
    int ct = mq*16 + lr;
    const float* ax = x + ((b*64 + th0 + (ct>>3))*64 + tw0 + (ct&7))*128;
    f32x4 acc[2] = {};
#pragma unroll
    for (int k0 = 0; k0 < 4; ++k0){
      int koff = k0*32 + lk;
      short8 a = ldA(ax + koff);
#pragma unroll
      for (int fn = 0; fn < 2; ++fn)
        acc[fn] = __builtin_amdgcn_mfma_f32_16x16x32_bf16(a, ldB(Ws, (g*2+fn)*16+lr, koff), acc[fn], 0, 0, 0);
    }
#pragma unroll
    for (int fn = 0; fn < 2; ++fn){
      int col = (g*2+fn)*16 + lr;
      float bv = bqkv[col];
#pragma unroll
      for (int r = 0; r < 4; ++r){
        int row = mq*16 + ((l>>4)<<2) + r;
        Qs[row*136 + col] = f2b((acc[fn][r] + bv) * QSCALE);
      }
    }
  }
  __syncthreads();                                          // S2
  stageW(wqkv, 384, 128, Ws, t);
  __syncthreads();                                          // S3

  // ---- K GEMM: waves 0..12 each own one M-frag of the 196-token halo ----
  if (wv < 13){
    int tok = wv*16 + lr; tok = tok < 196 ? tok : 195;
    int hr = tok/14, hc = tok - hr*14;
    const float* ax = x + ((b*64 + bi0+hr)*64 + bj0+hc)*128;
    f32x4 acc[8] = {};
#pragma unroll
    for (int k0 = 0; k0 < 4; ++k0){
      int koff = k0*32 + lk;
      short8 a = ldA(ax + koff);
#pragma unroll
      for (int fn = 0; fn < 8; ++fn)
        acc[fn] = __builtin_amdgcn_mfma_f32_16x16x32_bf16(a, ldB(Ws, fn*16+lr, koff), acc[fn], 0, 0, 0);
    }
#pragma unroll
    for (int fn = 0; fn < 8; ++fn){
      int col = fn*16 + lr;
      float bv = bqkv[128 + col];
#pragma unroll
      for (int r = 0; r < 4; ++r){
        int row = wv*16 + ((l>>4)<<2) + r;
        if (row < 196) Ks[row*136 + col] = f2b(acc[fn][r] + bv);
      }
    }
  }
  __syncthreads();                                          // S4
  stageW(wqkv, 384, 256, Ws, t);
  __syncthreads();                                          // S5

  // ---- V GEMM ----
  if (wv < 13){
    int tok = wv*16 + lr; tok = tok < 196 ? tok : 195;
    int hr = tok/14, hc = tok - hr*14;
    const float* ax = x + ((b*64 + bi0+hr)*64 + bj0+hc)*128;
    f32x4 acc[8] = {};
#pragma unroll
    for (int k0 = 0; k0 < 4; ++k0){
      int koff = k0*32 + lk;
      short8 a = ldA(ax + koff);
#pragma unroll
      for (int fn = 0; fn < 8; ++fn)
        acc[fn] = __builtin_amdgcn_mfma_f32_16x16x32_bf16(a, ldB(Ws, fn*16+lr, koff), acc[fn], 0, 0, 0);
    }
#pragma unroll
    for (int fn = 0; fn < 8; ++fn){
      int col = fn*16 + lr;
      float bv = bqkv[256 + col];
#pragma unroll
      for (int r = 0; r < 4; ++r){
        int row = wv*16 + ((l>>4)<<2) + r;
        if (row < 196) Vs[row*136 + col] = f2b(acc[fn][r] + bv);
      }
    }
  }
  __syncthreads();                                          // S6a

  // stage w_proj; latency hides under attention
  stageW(wproj, 128, 0, Ws, t);

  // ---- attention: thread = (token lt, head h, quarter p) ----
  const int lt = t >> 4, h = (t >> 2) & 3, p = t & 3;
  const int ti = th0 + (lt >> 3), tj = tw0 + (lt & 7);
  const int si = min(max(ti-3,0),57), sj = min(max(tj-3,0),57);
  const int li = si - bi0, lj = sj - bj0;
  const int ri = si - ti + 6, rj = sj - tj + 6;
  const int tbase = li*14 + lj;
  const int rbase = h*169 + ri*13 + rj;

  float q[32];
#pragma unroll
  for (int j = 0; j < 4; ++j){
    u16x8 u = *(const u16x8*)&Qs[lt*136 + h*32 + j*8];
#pragma unroll
    for (int e = 0; e < 8; ++e) q[j*8+e] = b2f(u[e]);
  }

  float s[13]; int toks[13];
  float mx = -1e30f;
#pragma unroll
  for (int it = 0; it < 13; ++it){
    int n = p + (it << 2);
    bool ok = (n < 49);
    int nn = ok ? n : 48;
    int pi = nn / 7, pj = nn - pi*7;
    int tok = tbase + pi*14 + pj;
    toks[it] = tok;
    float acc = rs[rbase + pi*13 + pj];
#pragma unroll
    for (int j = 0; j < 4; ++j){
      u16x8 kk = *(const u16x8*)&Ks[tok*136 + h*32 + j*8];
#pragma unroll
      for (int e = 0; e < 8; ++e) acc += q[j*8+e]*b2f(kk[e]);
    }
    s[it] = ok ? acc : -1e30f;
    mx = fmaxf(mx, s[it]);
  }
  mx = fmaxf(mx, __shfl_xor(mx, 1));
  mx = fmaxf(mx, __shfl_xor(mx, 2));
  __syncthreads();                                          // S6b: q reads done

  float lsum = 0.f, o[32];
#pragma unroll
  for (int d = 0; d < 32; ++d) o[d] = 0.f;
#pragma unroll
  for (int it = 0; it < 13; ++it){
    float e = __expf(s[it] - mx);
    lsum += e;
    int tok = toks[it];
#pragma unroll
    for (int j = 0; j < 4; ++j){
      u16x8 vvv = *(const u16x8*)&Vs[tok*136 + h*32 + j*8];
#pragma unroll
      for (int e2 = 0; e2 < 8; ++e2) o[j*8+e2] += e*b2f(vvv[e2]);
    }
  }
  lsum += __shfl_xor(lsum, 1);
  lsum += __shfl_xor(lsum, 2);
#pragma unroll
  for (int d = 0; d < 32; ++d) o[d] += __shfl_xor(o[d], 1);
#pragma unroll
  for (int d = 0; d < 32; ++d) o[d] += __shfl_xor(o[d], 2);

  float inv = 1.f / lsum;
  {
    u16x8 w8;
#pragma unroll
    for (int e = 0; e < 8; ++e) w8[e] = f2b(o[p*8+e]*inv);
    *(u16x8*)&Qs[lt*136 + h*32 + p*8] = w8;                 // ao -> Qs
  }
  __syncthreads();                                          // S7

  // ---- proj GEMM: wave = (m-frag wv>>2, n-pair wv&3) ----
  {
    const int mq = wv >> 2, g = wv & 3;
    f32x4 acc[2] = {};
#pragma unroll
    for (int k0 = 0; k0 < 4; ++k0){
      int koff = k0*32 + lk;
      short8 a = *(const short8*)&Qs[(mq*16 + lr)*136 + koff];
#pragma unroll
      for (int fn = 0; fn < 2; ++fn)
        acc[fn] = __builtin_amdgcn_mfma_f32_16x16x32_bf16(a, ldB(Ws, (g*2+fn)*16+lr, koff), acc[fn], 0, 0, 0);
    }
    float* C = (float*)Vs;   // [64][132] fp32
#pragma unroll
    for (int fn = 0; fn < 2; ++fn){
      int col = (g*2+fn)*16 + lr;
      float bv = bproj[col];
#pragma unroll
      for (int r = 0; r < 4; ++r){
        int row = mq*16 + ((l>>4)<<2) + r;
        C[row*132 + col] = acc[fn][r] + bv;
      }
    }
  }
  __syncthreads();                                          // S8
  {
    float* C = (float*)Vs;
    for (int c = t; c < 2048; c += 1024){
      int row = c >> 5, colc = (c & 31) << 2;
      int gtok = ((b*64 + th0 + (row>>3))*64 + tw0 + (row&7))*128;
      *(f4*)&out[gtok + colc] = *(const f4*)&C[row*132 + colc];
    }
  }
}

extern "C" void kernel_launch(void* const* d_in, const int* in_sizes, int n_in,
                              void* d_out, int out_size, void* d_ws, size_t ws_size,
                              hipStream_t stream) {
  const float* x      = (const float*)d_in[0];
  const float* w_qkv  = (const float*)d_in[1];
  const float* b_qkv  = (const float*)d_in[2];
  const float* rpb    = (const float*)d_in[3];
  const float* w_proj = (const float*)d_in[4];
  const float* b_proj = (const float*)d_in[5];
  float* out = (float*)d_out;

  k_fused<<<dim3(8, 8, 4), 1024, 0, stream>>>(x, w_qkv, b_qkv, rpb, w_proj, b_proj, out);
}

// Round 7
// 52.514 us; speedup vs baseline: 1.6071x; 1.6071x over previous
//
#include <hip/hip_runtime.h>
#include <hip/hip_bf16.h>

typedef float f4 __attribute__((ext_vector_type(4)));
typedef float f32x4 __attribute__((ext_vector_type(4)));
typedef unsigned short u16x8 __attribute__((ext_vector_type(8)));
typedef short short8 __attribute__((ext_vector_type(8)));
typedef unsigned int uint2v __attribute__((ext_vector_type(2)));

#define QSCALE 0.17677669529663689f  // 32^-0.5

__device__ inline float b2f(unsigned short u){
  union{unsigned int i; float f;} z; z.i = ((unsigned int)u)<<16; return z.f;
}
__device__ inline unsigned short f2b(float f){
  union{float f; unsigned int i;} z; z.f=f;
  unsigned int i = z.i;
  return (unsigned short)((i + 0x7FFFu + ((i>>16)&1u)) >> 16);
}

// stage a [128k][128n] fp32 weight panel -> Ws[n][k] bf16, XOR-swizzled (512 thr)
__device__ inline void stageW(const float* __restrict__ w, int stride, int n0,
                              short* Ws, int t){
  for (int c = t; c < 1024; c += 512){
    int kb = c >> 5, nb = c & 31;
    const float* p = &w[(kb*4)*stride + n0 + nb*4];
    f4 r0 = *(const f4*)p;
    f4 r1 = *(const f4*)(p + stride);
    f4 r2 = *(const f4*)(p + 2*stride);
    f4 r3 = *(const f4*)(p + 3*stride);
#pragma unroll
    for (int j = 0; j < 4; ++j){
      int n = nb*4 + j;
      uint2v val;
      val[0] = (unsigned int)f2b(r0[j]) | ((unsigned int)f2b(r1[j])<<16);
      val[1] = (unsigned int)f2b(r2[j]) | ((unsigned int)f2b(r3[j])<<16);
      int byte = (n<<8) + (kb<<3);
      *(uint2v*)((char*)Ws + (byte ^ ((n&7)<<4))) = val;
    }
  }
}

__device__ inline short8 ldB(const short* Ws, int rn, int koff){
  int byte = (rn<<8) + (koff<<1);
  return *(const short8*)((const char*)Ws + (byte ^ ((rn&7)<<4)));
}

__device__ inline short8 ldA(const float* p){
  f4 lo = *(const f4*)p, hi = *(const f4*)(p+4);
  short8 r;
  r[0]=(short)f2b(lo[0]); r[1]=(short)f2b(lo[1]);
  r[2]=(short)f2b(lo[2]); r[3]=(short)f2b(lo[3]);
  r[4]=(short)f2b(hi[0]); r[5]=(short)f2b(hi[1]);
  r[6]=(short)f2b(hi[2]); r[7]=(short)f2b(hi[3]);
  return r;
}

// ============ fully fused neighborhood attention, 8 waves/block ============
// grid (8,8,4) = (tile_j, tile_i, batch), block 512 (8 waves), 1 block/CU.
__global__ __launch_bounds__(512, 2) void k_fused(
    const float* __restrict__ x,     const float* __restrict__ wqkv,
    const float* __restrict__ bqkv,  const float* __restrict__ rpb,
    const float* __restrict__ wproj, const float* __restrict__ bproj,
    float* __restrict__ out)
{
  __shared__ short lds[79752];           // 159,504 B
  short* Qs = lds;                       // [64][136]  q, later ao
  short* Ks = lds + 8704;                // [196][136] k halo
  short* Vs = Ks + 26656;                // [196][136] v halo, later fp32 C
  short* Ws = Vs + 26656;                // [128][128] swizzled weight panel
  float* rs = (float*)(Ws + 16384);      // [676] rpb

  const int t  = threadIdx.x;
  const int b  = blockIdx.z;
  const int th0 = blockIdx.y * 8, tw0 = blockIdx.x * 8;
  const int bi0 = min(max(th0-3,0),50), bj0 = min(max(tw0-3,0),50);
  const int wv = t >> 6, l = t & 63;
  const int lr = l & 15, lk = (l >> 4) << 3;

  // phase 0: stage wq panel + rpb
  stageW(wqkv, 384, 0, Ws, t);
  for (int c = t; c < 676; c += 512) rs[c] = rpb[c];
  __syncthreads();                                          // S1

  // ---- Q GEMM: wave = (m-frag wv>>1, n-half wv&1), acc[4] ----
  {
    const int mq = wv >> 1, g = wv & 1;
    int ct = mq*16 + lr;
    const float* ax = x + ((b*64 + th0 + (ct>>3))*64 + tw0 + (ct&7))*128;
    f32x4 acc[4] = {};
#pragma unroll
    for (int k0 = 0; k0 < 4; ++k0){
      int koff = k0*32 + lk;
      short8 a = ldA(ax + koff);
#pragma unroll
      for (int fn = 0; fn < 4; ++fn)
        acc[fn] = __builtin_amdgcn_mfma_f32_16x16x32_bf16(a, ldB(Ws, (g*4+fn)*16+lr, koff), acc[fn], 0, 0, 0);
    }
#pragma unroll
    for (int fn = 0; fn < 4; ++fn){
      int col = (g*4+fn)*16 + lr;
      float bv = bqkv[col];
#pragma unroll
      for (int r = 0; r < 4; ++r){
        int row = mq*16 + ((l>>4)<<2) + r;
        Qs[row*136 + col] = f2b((acc[fn][r] + bv) * QSCALE);
      }
    }
  }
  __syncthreads();                                          // S2
  stageW(wqkv, 384, 128, Ws, t);
  __syncthreads();                                          // S3

  // ---- K GEMM: 13 M-frags; wave wv does frags {wv, wv+8} ----
#pragma unroll
  for (int pass = 0; pass < 2; ++pass){
    int fmi = wv + pass*8;
    if (fmi < 13){
      int tok = fmi*16 + lr; tok = tok < 196 ? tok : 195;
      int hr = tok/14, hc = tok - hr*14;
      const float* ax = x + ((b*64 + bi0+hr)*64 + bj0+hc)*128;
      f32x4 acc[8] = {};
#pragma unroll
      for (int k0 = 0; k0 < 4; ++k0){
        int koff = k0*32 + lk;
        short8 a = ldA(ax + koff);
#pragma unroll
        for (int fn = 0; fn < 8; ++fn)
          acc[fn] = __builtin_amdgcn_mfma_f32_16x16x32_bf16(a, ldB(Ws, fn*16+lr, koff), acc[fn], 0, 0, 0);
      }
#pragma unroll
      for (int fn = 0; fn < 8; ++fn){
        int col = fn*16 + lr;
        float bv = bqkv[128 + col];
#pragma unroll
        for (int r = 0; r < 4; ++r){
          int row = fmi*16 + ((l>>4)<<2) + r;
          if (row < 196) Ks[row*136 + col] = f2b(acc[fn][r] + bv);
        }
      }
    }
  }
  __syncthreads();                                          // S4
  stageW(wqkv, 384, 256, Ws, t);
  __syncthreads();                                          // S5

  // ---- V GEMM ----
#pragma unroll
  for (int pass = 0; pass < 2; ++pass){
    int fmi = wv + pass*8;
    if (fmi < 13){
      int tok = fmi*16 + lr; tok = tok < 196 ? tok : 195;
      int hr = tok/14, hc = tok - hr*14;
      const float* ax = x + ((b*64 + bi0+hr)*64 + bj0+hc)*128;
      f32x4 acc[8] = {};
#pragma unroll
      for (int k0 = 0; k0 < 4; ++k0){
        int koff = k0*32 + lk;
        short8 a = ldA(ax + koff);
#pragma unroll
        for (int fn = 0; fn < 8; ++fn)
          acc[fn] = __builtin_amdgcn_mfma_f32_16x16x32_bf16(a, ldB(Ws, fn*16+lr, koff), acc[fn], 0, 0, 0);
      }
#pragma unroll
      for (int fn = 0; fn < 8; ++fn){
        int col = fn*16 + lr;
        float bv = bqkv[256 + col];
#pragma unroll
        for (int r = 0; r < 4; ++r){
          int row = fmi*16 + ((l>>4)<<2) + r;
          if (row < 196) Vs[row*136 + col] = f2b(acc[fn][r] + bv);
        }
      }
    }
  }
  __syncthreads();                                          // S6a

  // stage w_proj; latency hides under attention
  stageW(wproj, 128, 0, Ws, t);

  // ---- attention: thread = (token lt, head h, parity p) ----
  const int lt = t >> 3, h = (t >> 1) & 3, p = t & 1;
  const int ti = th0 + (lt >> 3), tj = tw0 + (lt & 7);
  const int si = min(max(ti-3,0),57), sj = min(max(tj-3,0),57);
  const int li = si - bi0, lj = sj - bj0;
  const int ri = si - ti + 6, rj = sj - tj + 6;
  const int tbase = li*14 + lj;
  const int rbase = h*169 + ri*13 + rj;

  float q[32];
#pragma unroll
  for (int j = 0; j < 4; ++j){
    u16x8 u = *(const u16x8*)&Qs[lt*136 + h*32 + j*8];
#pragma unroll
    for (int e = 0; e < 8; ++e) q[j*8+e] = b2f(u[e]);
  }

  float s[25]; int toks[25];
  float mx = -1e30f;
#pragma unroll
  for (int it = 0; it < 25; ++it){
    int n = p + (it << 1);
    bool ok = (n < 49);
    int nn = ok ? n : 48;
    int pi = nn / 7, pj = nn - pi*7;
    int tok = tbase + pi*14 + pj;
    toks[it] = tok;
    float acc = rs[rbase + pi*13 + pj];
#pragma unroll
    for (int j = 0; j < 4; ++j){
      u16x8 kk = *(const u16x8*)&Ks[tok*136 + h*32 + j*8];
#pragma unroll
      for (int e = 0; e < 8; ++e) acc += q[j*8+e]*b2f(kk[e]);
    }
    s[it] = ok ? acc : -1e30f;
    mx = fmaxf(mx, s[it]);
  }
  mx = fmaxf(mx, __shfl_xor(mx, 1));
  __syncthreads();                                          // S6b: q reads done

  float lsum = 0.f, o[32];
#pragma unroll
  for (int d = 0; d < 32; ++d) o[d] = 0.f;
#pragma unroll
  for (int it = 0; it < 25; ++it){
    float e = __expf(s[it] - mx);
    lsum += e;
    int tok = toks[it];
#pragma unroll
    for (int j = 0; j < 4; ++j){
      u16x8 vvv = *(const u16x8*)&Vs[tok*136 + h*32 + j*8];
#pragma unroll
      for (int e2 = 0; e2 < 8; ++e2) o[j*8+e2] += e*b2f(vvv[e2]);
    }
  }
  lsum += __shfl_xor(lsum, 1);
#pragma unroll
  for (int d = 0; d < 32; ++d) o[d] += __shfl_xor(o[d], 1);

  float inv = 1.f / lsum;
#pragma unroll
  for (int j = 0; j < 2; ++j){
    u16x8 w8;
#pragma unroll
    for (int e = 0; e < 8; ++e) w8[e] = f2b(o[p*16 + j*8 + e]*inv);
    *(u16x8*)&Qs[lt*136 + h*32 + p*16 + j*8] = w8;          // ao -> Qs
  }
  __syncthreads();                                          // S7

  // ---- proj GEMM: wave = (m-frag wv>>1, n-half wv&1) ----
  {
    const int mq = wv >> 1, g = wv & 1;
    f32x4 acc[4] = {};
#pragma unroll
    for (int k0 = 0; k0 < 4; ++k0){
      int koff = k0*32 + lk;
      short8 a = *(const short8*)&Qs[(mq*16 + lr)*136 + koff];
#pragma unroll
      for (int fn = 0; fn < 4; ++fn)
        acc[fn] = __builtin_amdgcn_mfma_f32_16x16x32_bf16(a, ldB(Ws, (g*4+fn)*16+lr, koff), acc[fn], 0, 0, 0);
    }
    float* C = (float*)Vs;   // [64][132] fp32
#pragma unroll
    for (int fn = 0; fn < 4; ++fn){
      int col = (g*4+fn)*16 + lr;
      float bv = bproj[col];
#pragma unroll
      for (int r = 0; r < 4; ++r){
        int row = mq*16 + ((l>>4)<<2) + r;
        C[row*132 + col] = acc[fn][r] + bv;
      }
    }
  }
  __syncthreads();                                          // S8
  {
    float* C = (float*)Vs;
    for (int c = t; c < 2048; c += 512){
      int row = c >> 5, colc = (c & 31) << 2;
      int gtok = ((b*64 + th0 + (row>>3))*64 + tw0 + (row&7))*128;
      *(f4*)&out[gtok + colc] = *(const f4*)&C[row*132 + colc];
    }
  }
}

extern "C" void kernel_launch(void* const* d_in, const int* in_sizes, int n_in,
                              void* d_out, int out_size, void* d_ws, size_t ws_size,
                              hipStream_t stream) {
  const float* x      = (const float*)d_in[0];
  const float* w_qkv  = (const float*)d_in[1];
  const float* b_qkv  = (const float*)d_in[2];
  const float* rpb    = (const float*)d_in[3];
  const float* w_proj = (const float*)d_in[4];
  const float* b_proj = (const float*)d_in[5];
  float* out = (float*)d_out;

  k_fused<<<dim3(8, 8, 4), 512, 0, stream>>>(x, w_qkv, b_qkv, rpb, w_proj, b_proj, out);
}

// Round 8
// 50.941 us; speedup vs baseline: 1.6567x; 1.0309x over previous
//
#include <hip/hip_runtime.h>
#include <hip/hip_bf16.h>

typedef float f4 __attribute__((ext_vector_type(4)));
typedef float f32x4 __attribute__((ext_vector_type(4)));
typedef unsigned short u16x8 __attribute__((ext_vector_type(8)));
typedef short short8 __attribute__((ext_vector_type(8)));
typedef unsigned int uint2v __attribute__((ext_vector_type(2)));

#define QSCALE 0.17677669529663689f  // 32^-0.5

__device__ inline float b2f(unsigned short u){
  union{unsigned int i; float f;} z; z.i = ((unsigned int)u)<<16; return z.f;
}
__device__ inline unsigned short f2b(float f){
  union{float f; unsigned int i;} z; z.f=f;
  unsigned int i = z.i;
  return (unsigned short)((i + 0x7FFFu + ((i>>16)&1u)) >> 16);
}

// stage a [128k][128n] fp32 weight panel -> Ws[n][k] bf16, XOR-swizzled (512 thr)
__device__ inline void stageW(const float* __restrict__ w, int stride, int n0,
                              short* Ws, int t){
  for (int c = t; c < 1024; c += 512){
    int kb = c >> 5, nb = c & 31;
    const float* p = &w[(kb*4)*stride + n0 + nb*4];
    f4 r0 = *(const f4*)p;
    f4 r1 = *(const f4*)(p + stride);
    f4 r2 = *(const f4*)(p + 2*stride);
    f4 r3 = *(const f4*)(p + 3*stride);
#pragma unroll
    for (int j = 0; j < 4; ++j){
      int n = nb*4 + j;
      uint2v val;
      val[0] = (unsigned int)f2b(r0[j]) | ((unsigned int)f2b(r1[j])<<16);
      val[1] = (unsigned int)f2b(r2[j]) | ((unsigned int)f2b(r3[j])<<16);
      int byte = (n<<8) + (kb<<3);
      *(uint2v*)((char*)Ws + (byte ^ ((n&7)<<4))) = val;
    }
  }
}

__device__ inline short8 ldB(const short* Ws, int rn, int koff){
  int byte = (rn<<8) + (koff<<1);
  return *(const short8*)((const char*)Ws + (byte ^ ((rn&7)<<4)));
}

__device__ inline short8 ldA(const float* p){
  f4 lo = *(const f4*)p, hi = *(const f4*)(p+4);
  short8 r;
  r[0]=(short)f2b(lo[0]); r[1]=(short)f2b(lo[1]);
  r[2]=(short)f2b(lo[2]); r[3]=(short)f2b(lo[3]);
  r[4]=(short)f2b(hi[0]); r[5]=(short)f2b(hi[1]);
  r[6]=(short)f2b(hi[2]); r[7]=(short)f2b(hi[3]);
  return r;
}

// ============ fully fused neighborhood attention, 8 waves/block ============
// grid (8,8,4) = (tile_j, tile_i, batch), block 512 (8 waves), 1 block/CU.
// NOTE: no min-waves arg in launch_bounds — (512,2) capped VGPR at 128 and
// spilled ~40 slots/thread (45 MB scratch writes, r7). Plain (512) forces
// <=256 VGPR (block residency) and the live set (~180) fits.
__global__ __launch_bounds__(512) void k_fused(
    const float* __restrict__ x,     const float* __restrict__ wqkv,
    const float* __restrict__ bqkv,  const float* __restrict__ rpb,
    const float* __restrict__ wproj, const float* __restrict__ bproj,
    float* __restrict__ out)
{
  __shared__ short lds[79752];           // 159,504 B
  short* Qs = lds;                       // [64][136]  q, later ao
  short* Ks = lds + 8704;                // [196][136] k halo
  short* Vs = Ks + 26656;                // [196][136] v halo, later fp32 C
  short* Ws = Vs + 26656;                // [128][128] swizzled weight panel
  float* rs = (float*)(Ws + 16384);      // [676] rpb

  const int t  = threadIdx.x;
  const int b  = blockIdx.z;
  const int th0 = blockIdx.y * 8, tw0 = blockIdx.x * 8;
  const int bi0 = min(max(th0-3,0),50), bj0 = min(max(tw0-3,0),50);
  const int wv = t >> 6, l = t & 63;
  const int lr = l & 15, lk = (l >> 4) << 3;

  // phase 0: stage wq panel + rpb
  stageW(wqkv, 384, 0, Ws, t);
  for (int c = t; c < 676; c += 512) rs[c] = rpb[c];
  __syncthreads();                                          // S1

  // ---- Q GEMM: wave = (m-frag wv>>1, n-half wv&1), acc[4] ----
  {
    const int mq = wv >> 1, g = wv & 1;
    int ct = mq*16 + lr;
    const float* ax = x + ((b*64 + th0 + (ct>>3))*64 + tw0 + (ct&7))*128;
    f32x4 acc[4] = {};
#pragma unroll
    for (int k0 = 0; k0 < 4; ++k0){
      int koff = k0*32 + lk;
      short8 a = ldA(ax + koff);
#pragma unroll
      for (int fn = 0; fn < 4; ++fn)
        acc[fn] = __builtin_amdgcn_mfma_f32_16x16x32_bf16(a, ldB(Ws, (g*4+fn)*16+lr, koff), acc[fn], 0, 0, 0);
    }
#pragma unroll
    for (int fn = 0; fn < 4; ++fn){
      int col = (g*4+fn)*16 + lr;
      float bv = bqkv[col];
#pragma unroll
      for (int r = 0; r < 4; ++r){
        int row = mq*16 + ((l>>4)<<2) + r;
        Qs[row*136 + col] = f2b((acc[fn][r] + bv) * QSCALE);
      }
    }
  }
  __syncthreads();                                          // S2
  stageW(wqkv, 384, 128, Ws, t);
  __syncthreads();                                          // S3

  // ---- K GEMM: 13 M-frags; wave wv does frags {wv, wv+8} ----
#pragma unroll
  for (int pass = 0; pass < 2; ++pass){
    int fmi = wv + pass*8;
    if (fmi < 13){
      int tok = fmi*16 + lr; tok = tok < 196 ? tok : 195;
      int hr = tok/14, hc = tok - hr*14;
      const float* ax = x + ((b*64 + bi0+hr)*64 + bj0+hc)*128;
      f32x4 acc[8] = {};
#pragma unroll
      for (int k0 = 0; k0 < 4; ++k0){
        int koff = k0*32 + lk;
        short8 a = ldA(ax + koff);
#pragma unroll
        for (int fn = 0; fn < 8; ++fn)
          acc[fn] = __builtin_amdgcn_mfma_f32_16x16x32_bf16(a, ldB(Ws, fn*16+lr, koff), acc[fn], 0, 0, 0);
      }
#pragma unroll
      for (int fn = 0; fn < 8; ++fn){
        int col = fn*16 + lr;
        float bv = bqkv[128 + col];
#pragma unroll
        for (int r = 0; r < 4; ++r){
          int row = fmi*16 + ((l>>4)<<2) + r;
          if (row < 196) Ks[row*136 + col] = f2b(acc[fn][r] + bv);
        }
      }
    }
  }
  __syncthreads();                                          // S4
  stageW(wqkv, 384, 256, Ws, t);
  __syncthreads();                                          // S5

  // ---- V GEMM ----
#pragma unroll
  for (int pass = 0; pass < 2; ++pass){
    int fmi = wv + pass*8;
    if (fmi < 13){
      int tok = fmi*16 + lr; tok = tok < 196 ? tok : 195;
      int hr = tok/14, hc = tok - hr*14;
      const float* ax = x + ((b*64 + bi0+hr)*64 + bj0+hc)*128;
      f32x4 acc[8] = {};
#pragma unroll
      for (int k0 = 0; k0 < 4; ++k0){
        int koff = k0*32 + lk;
        short8 a = ldA(ax + koff);
#pragma unroll
        for (int fn = 0; fn < 8; ++fn)
          acc[fn] = __builtin_amdgcn_mfma_f32_16x16x32_bf16(a, ldB(Ws, fn*16+lr, koff), acc[fn], 0, 0, 0);
      }
#pragma unroll
      for (int fn = 0; fn < 8; ++fn){
        int col = fn*16 + lr;
        float bv = bqkv[256 + col];
#pragma unroll
        for (int r = 0; r < 4; ++r){
          int row = fmi*16 + ((l>>4)<<2) + r;
          if (row < 196) Vs[row*136 + col] = f2b(acc[fn][r] + bv);
        }
      }
    }
  }
  __syncthreads();                                          // S6a

  // stage w_proj; latency hides under attention
  stageW(wproj, 128, 0, Ws, t);

  // ---- attention: thread = (token lt, head h, parity p) ----
  const int lt = t >> 3, h = (t >> 1) & 3, p = t & 1;
  const int ti = th0 + (lt >> 3), tj = tw0 + (lt & 7);
  const int si = min(max(ti-3,0),57), sj = min(max(tj-3,0),57);
  const int li = si - bi0, lj = sj - bj0;
  const int ri = si - ti + 6, rj = sj - tj + 6;
  const int tbase = li*14 + lj;
  const int rbase = h*169 + ri*13 + rj;

  float q[32];
#pragma unroll
  for (int j = 0; j < 4; ++j){
    u16x8 u = *(const u16x8*)&Qs[lt*136 + h*32 + j*8];
#pragma unroll
    for (int e = 0; e < 8; ++e) q[j*8+e] = b2f(u[e]);
  }

  float s[25];
  float mx = -1e30f;
#pragma unroll
  for (int it = 0; it < 25; ++it){
    int n = p + (it << 1);
    bool ok = (n < 49);
    int nn = ok ? n : 48;
    int pi = nn / 7, pj = nn - pi*7;
    int tok = tbase + pi*14 + pj;
    float acc = rs[rbase + pi*13 + pj];
#pragma unroll
    for (int j = 0; j < 4; ++j){
      u16x8 kk = *(const u16x8*)&Ks[tok*136 + h*32 + j*8];
#pragma unroll
      for (int e = 0; e < 8; ++e) acc += q[j*8+e]*b2f(kk[e]);
    }
    s[it] = ok ? acc : -1e30f;
    mx = fmaxf(mx, s[it]);
  }
  mx = fmaxf(mx, __shfl_xor(mx, 1));
  __syncthreads();                                          // S6b: q reads done

  float lsum = 0.f, o[32];
#pragma unroll
  for (int d = 0; d < 32; ++d) o[d] = 0.f;
#pragma unroll
  for (int it = 0; it < 25; ++it){
    int n = p + (it << 1);
    int nn = n < 49 ? n : 48;
    int pi = nn / 7, pj = nn - pi*7;
    int tok = tbase + pi*14 + pj;                           // recomputed (saves 25 VGPR)
    float e = __expf(s[it] - mx);
    lsum += e;
#pragma unroll
    for (int j = 0; j < 4; ++j){
      u16x8 vvv = *(const u16x8*)&Vs[tok*136 + h*32 + j*8];
#pragma unroll
      for (int e2 = 0; e2 < 8; ++e2) o[j*8+e2] += e*b2f(vvv[e2]);
    }
  }
  lsum += __shfl_xor(lsum, 1);
#pragma unroll
  for (int d = 0; d < 32; ++d) o[d] += __shfl_xor(o[d], 1);

  float inv = 1.f / lsum;
#pragma unroll
  for (int j = 0; j < 2; ++j){
    u16x8 w8;
#pragma unroll
    for (int e = 0; e < 8; ++e) w8[e] = f2b(o[p*16 + j*8 + e]*inv);
    *(u16x8*)&Qs[lt*136 + h*32 + p*16 + j*8] = w8;          // ao -> Qs
  }
  __syncthreads();                                          // S7

  // ---- proj GEMM: wave = (m-frag wv>>1, n-half wv&1) ----
  {
    const int mq = wv >> 1, g = wv & 1;
    f32x4 acc[4] = {};
#pragma unroll
    for (int k0 = 0; k0 < 4; ++k0){
      int koff = k0*32 + lk;
      short8 a = *(const short8*)&Qs[(mq*16 + lr)*136 + koff];
#pragma unroll
      for (int fn = 0; fn < 4; ++fn)
        acc[fn] = __builtin_amdgcn_mfma_f32_16x16x32_bf16(a, ldB(Ws, (g*4+fn)*16+lr, koff), acc[fn], 0, 0, 0);
    }
    float* C = (float*)Vs;   // [64][132] fp32
#pragma unroll
    for (int fn = 0; fn < 4; ++fn){
      int col = (g*4+fn)*16 + lr;
      float bv = bproj[col];
#pragma unroll
      for (int r = 0; r < 4; ++r){
        int row = mq*16 + ((l>>4)<<2) + r;
        C[row*132 + col] = acc[fn][r] + bv;
      }
    }
  }
  __syncthreads();                                          // S8
  {
    float* C = (float*)Vs;
    for (int c = t; c < 2048; c += 512){
      int row = c >> 5, colc = (c & 31) << 2;
      int gtok = ((b*64 + th0 + (row>>3))*64 + tw0 + (row&7))*128;
      *(f4*)&out[gtok + colc] = *(const f4*)&C[row*132 + colc];
    }
  }
}

extern "C" void kernel_launch(void* const* d_in, const int* in_sizes, int n_in,
                              void* d_out, int out_size, void* d_ws, size_t ws_size,
                              hipStream_t stream) {
  const float* x      = (const float*)d_in[0];
  const float* w_qkv  = (const float*)d_in[1];
  const float* b_qkv  = (const float*)d_in[2];
  const float* rpb    = (const float*)d_in[3];
  const float* w_proj = (const float*)d_in[4];
  const float* b_proj = (const float*)d_in[5];
  float* out = (float*)d_out;

  k_fused<<<dim3(8, 8, 4), 512, 0, stream>>>(x, w_qkv, b_qkv, rpb, w_proj, b_proj, out);
}